// Round 10
// baseline (241.007 us; speedup 1.0000x reference)
//
#include <hip/hip_runtime.h>
#include <hip/hip_bf16.h>
#include <stdint.h>

// Problem constants (S=1024, B=2 -> T=2048 tokens)
#define TT 2048
#define DD 512
#define FF 2048
#define EE 8

typedef unsigned short u16;
typedef __attribute__((ext_vector_type(8))) unsigned short ushort8v;
typedef __attribute__((ext_vector_type(8))) short short8;     // bf16x8 frag
typedef __attribute__((ext_vector_type(4))) float float4v;

__device__ __forceinline__ u16 f2bf(float f) {
    unsigned u = __float_as_uint(f);
    u += 0x7FFF + ((u >> 16) & 1);   // round-to-nearest-even
    return (u16)(u >> 16);
}

__device__ __forceinline__ void gl_lds16(const u16* g, u16* l) {
    __builtin_amdgcn_global_load_lds(
        (const __attribute__((address_space(1))) unsigned int*)g,
        (__attribute__((address_space(3))) unsigned int*)l, 16, 0, 0);
}

// ---------------- workspace layout (bytes) ----------------
#define WS_HB   0ull                                // hbuf bf16 [6144][2048]
#define WS_XG   (WS_HB + 6144ull*2048*2)            // xg bf16 [2048][512]
#define WS_WT1  (WS_XG + 2048ull*512*2)             // W1t bf16 [9][F][D]
#define WS_ME   (WS_WT1 + 9ull*2048*512*2)          // int  metaE[4096]
#define WS_MW   (WS_ME + 16384)                     // float metaW[4096]
#define WS_WT2  (WS_MW + 16384)                     // W2t bf16 [9][D][F]
#define WS_NEED (WS_WT2 + 9ull*2048*512*2)          // ~65.1 MB

// ---------------- conv unit: fp32 [R][C] 64x64 tile -> bf16 [C][R] ----------------
__device__ __forceinline__ void conv_unit(int j, const float* __restrict__ srcE,
                                          const float* __restrict__ srcS,
                                          u16* __restrict__ dst,
                                          int R, int C, int shC, u16* Ls) {
    int mid = j >> 8, t2 = j & 255;
    int tr = t2 >> shC, tc = t2 & ((1 << shC) - 1);
    int r0 = tr * 64, c0 = tc * 64;
    const float* src = (mid < 8) ? srcE + (size_t)mid * R * C : srcS;
    u16* dstm = dst + (size_t)mid * R * C;
    int t = threadIdx.x;
#pragma unroll
    for (int i = 0; i < 4; ++i) {
        int rr = (t >> 4) + i * 16;
        int cc = (t & 15) * 4;
        float4v v = *(const float4v*)(src + (size_t)(r0 + rr) * C + c0 + cc);
#pragma unroll
        for (int jx = 0; jx < 4; ++jx) Ls[(cc + jx) * 72 + rr] = f2bf(v[jx]);
    }
    __syncthreads();
#pragma unroll
    for (int jj = 0; jj < 2; ++jj) {
        int slot = t + jj * 256;
        int cc = slot >> 3, r8 = (slot & 7) * 8;
        ushort8v o = *(const ushort8v*)&Ls[cc * 72 + r8];
        *(ushort8v*)(dstm + (size_t)(c0 + cc) * R + r0 + r8) = o;
    }
}

// ---------------- gate: one wave per token (fp32 logits = np ref) ----------------
__device__ __forceinline__ void gate_wave(int t, int lane,
                                          const float* __restrict__ x,
                                          const float* __restrict__ Wg,
                                          const float* __restrict__ bg,
                                          int* __restrict__ metaE,
                                          float* __restrict__ metaW,
                                          u16* __restrict__ xg) {
    const float* xp = x + (size_t)t * DD + lane * 8;
    float4v x0 = *(const float4v*)xp;
    float4v x1 = *(const float4v*)(xp + 4);
    float xf[8] = {x0[0], x0[1], x0[2], x0[3], x1[0], x1[1], x1[2], x1[3]};
    float acc[EE] = {0.f, 0.f, 0.f, 0.f, 0.f, 0.f, 0.f, 0.f};
#pragma unroll
    for (int g = 0; g < 8; ++g) {
        const float* wp = Wg + (size_t)(lane * 8 + g) * EE;
        float4v w0 = *(const float4v*)wp;
        float4v w1 = *(const float4v*)(wp + 4);
        acc[0] += xf[g] * w0[0]; acc[1] += xf[g] * w0[1];
        acc[2] += xf[g] * w0[2]; acc[3] += xf[g] * w0[3];
        acc[4] += xf[g] * w1[0]; acc[5] += xf[g] * w1[1];
        acc[6] += xf[g] * w1[2]; acc[7] += xf[g] * w1[3];
    }
#pragma unroll
    for (int off = 1; off < 64; off <<= 1) {
#pragma unroll
        for (int e = 0; e < EE; ++e) acc[e] += __shfl_xor(acc[e], off, 64);
    }
    ushort8v xv;
#pragma unroll
    for (int jx = 0; jx < 4; ++jx) xv[jx] = f2bf(x0[jx]);
#pragma unroll
    for (int jx = 0; jx < 4; ++jx) xv[4 + jx] = f2bf(x1[jx]);
    *(ushort8v*)(xg + (size_t)t * DD + lane * 8) = xv;
    if (lane == 0) {
#pragma unroll
        for (int e = 0; e < EE; ++e) acc[e] += bg[e];
        int e0 = 0; float l0 = acc[0];
#pragma unroll
        for (int e = 1; e < EE; ++e) if (acc[e] > l0) { l0 = acc[e]; e0 = e; }
        int e1 = -1; float l1 = -3.4e38f;
#pragma unroll
        for (int e = 0; e < EE; ++e)
            if (e != e0 && acc[e] > l1) { l1 = acc[e]; e1 = e; }
        float ex = __expf(l1 - l0);
        float w0 = 1.f / (1.f + ex);
        metaE[2 * t] = e0; metaE[2 * t + 1] = e1;
        metaW[2 * t] = w0; metaW[2 * t + 1] = 1.f - w0;
    }
}

// ---------------- fused phase-1: conv1 + conv2 + gate + out-zero ----------------
__global__ __launch_bounds__(256) void fused1_k(
    const float* __restrict__ x, const float* __restrict__ Wg,
    const float* __restrict__ bg,
    const float* __restrict__ W1, const float* __restrict__ Ws1,
    const float* __restrict__ W2, const float* __restrict__ Ws2,
    float* __restrict__ out, u16* __restrict__ xg,
    u16* __restrict__ Wt1, u16* __restrict__ Wt2,
    int* __restrict__ metaE, float* __restrict__ metaW, int nconv) {
    __shared__ __align__(16) u16 Ls[64 * 72];
    int b = blockIdx.x, tid = threadIdx.x;
    if (b < nconv) {
        if (b < 2304) conv_unit(b, W1, Ws1, Wt1, DD, FF, 5, Ls);
        else          conv_unit(b - 2304, W2, Ws2, Wt2, FF, DD, 3, Ls);
    } else if (b < nconv + 512) {
        int gb = b - nconv;
        gate_wave(gb * 4 + (tid >> 6), tid & 63, x, Wg, bg, metaE, metaW, xg);
    } else {
        int zb = b - nconv - 512;
        float* op = out + (size_t)zb * 8192;
#pragma unroll
        for (int it = 0; it < 8; ++it)
            *(float4v*)(op + it * 1024 + tid * 4) = (float4v){0.f, 0.f, 0.f, 0.f};
    }
}

__global__ __launch_bounds__(256) void conv2_k(const float* __restrict__ W2,
                                               const float* __restrict__ Ws2,
                                               u16* __restrict__ Wt2) {
    __shared__ __align__(16) u16 Ls[64 * 72];
    conv_unit(blockIdx.x, W2, Ws2, Wt2, FF, DD, 3, Ls);
}

// ---------------- in-block rank: ballots + parallel scan + scatter -------------
// Scratch overlaid on tile buffers (caller provides). Produces:
//  offs8 (int[8], LDS), cnt via scanA[504+e], row2ent u16[4096] (LDS).
// All 256 threads. Caller must NOT have staged yet.
__device__ __forceinline__ void rank_inblock(
    const int* __restrict__ metaE, u16* er, int* scanA, int* scanB,
    int* offs8, u16* row2ent, int tid, int w, int lane, int** prefOut) {
    unsigned long long below = (lane == 0) ? 0ull : ((~0ull) >> (64 - lane));
    for (int s = w * 16; s < w * 16 + 16; ++s) {
        int entry = s * 64 + lane;
        int e = metaE[entry];
        int rk = 0;
#pragma unroll
        for (int x = 0; x < 8; ++x) {
            unsigned long long m = __ballot(e == x);
            if (e == x) rk = __popcll(m & below);
            if (lane == x) scanA[s * 8 + x] = __popcll(m);
        }
        er[entry] = (u16)(e | (rk << 4));
    }
    __syncthreads();
    int* a = scanA; int* b2 = scanB;
    for (int off = 1; off < 64; off <<= 1) {
        for (int s = tid; s < 512; s += 256) {
            int g = s >> 3;
            int v = a[s] + (g >= off ? a[s - (off << 3)] : 0);
            b2[s] = v;
        }
        __syncthreads();
        int* t = a; a = b2; b2 = t;
    }
    // a = inclusive per-expert prefix over segments; totals at a[504+e]
    if (tid < 8) {
        int s = 0;
        for (int x = 0; x < tid; ++x) s += a[504 + x];
        offs8[tid] = s;
    }
    __syncthreads();
    *prefOut = a;
}

__device__ __forceinline__ void rank_scatter(
    const u16* er, const int* pref, const int* offs8, u16* row2ent, int tid) {
    for (int i = 0; i < 16; ++i) {
        int entry = tid + i * 256;
        int v = er[entry];
        int x = v & 15, rk = v >> 4;
        int g = entry >> 6;
        int base = offs8[x] + (g ? pref[(g - 1) * 8 + x] : 0);
        row2ent[base + rk] = (u16)entry;
    }
}

// ---------------- GEMM A: h = relu(A @ W1 + b1). M=64,N=128,BK=32, dbuf ---------
// jobs: [0,512) shared (rt5|ct4); [512,4608) routed: jr = (rt*16+ct)*8 + e.
__global__ __launch_bounds__(256) void gemmA_k(
    const u16* __restrict__ xg, const u16* __restrict__ Wt1,
    const float* __restrict__ b1, const float* __restrict__ bs1,
    const int* __restrict__ metaE, const float* __restrict__ metaW,
    u16* __restrict__ hbuf) {
    __shared__ __align__(16) u16 As0[64 * 32];    // 4 KB
    __shared__ __align__(16) u16 As1[64 * 32];    // 4 KB
    __shared__ __align__(16) u16 Bs0[128 * 32];   // 8 KB
    __shared__ __align__(16) u16 Bs1[128 * 32];   // 8 KB
    int j = blockIdx.x, tid = threadIdx.x;
    int lane = tid & 63, w = tid >> 6, ln = lane & 15, quad = lane >> 4;
    int rsub = lane >> 2;
    int chunk = ((lane & 3) ^ ((lane >> 3) & 3)) * 8;

    int rt, ct, Mloc, hRowBase; bool routed = (j >= 512);
    const u16* Bsrc; const float* bias;
    int tok;   // per-lane A-gather token
    if (!routed) {
        rt = j >> 4; ct = j & 15; Mloc = 64;
        Bsrc = Wt1 + (size_t)8 * FF * DD; bias = bs1;
        hRowBase = 4096 + rt * 64;
        tok = rt * 64 + w * 16 + rsub;
    } else {
        int jr = j - 512; int e = jr & 7; int rc = jr >> 3;
        rt = rc >> 4; ct = rc & 15;
        // ---- in-block rank (scratch overlaid on tile buffers) ----
        u16* er = Bs0; u16* row2ent = Bs1;
        int* scanA = (int*)As0; int* scanB = scanA + 512;
        int* offs8 = (int*)As1;
        int* pref;
        rank_inblock(metaE, er, scanA, scanB, offs8, row2ent, tid, w, lane, &pref);
        int myCnt = pref[504 + e];
        if (rt * 64 >= myCnt) return;          // block-uniform
        rank_scatter(er, pref, offs8, row2ent, tid);
        __syncthreads();
        int rowBase = offs8[e] + rt * 64;
        Mloc = myCnt - rt * 64; if (Mloc > 64) Mloc = 64;
        int br = rowBase + w * 16 + rsub; if (br > 4095) br = 4095;
        tok = row2ent[br] >> 1;                // OOB rows: finite garbage, masked
        hRowBase = rowBase;
        Bsrc = Wt1 + (size_t)e * FF * DD; bias = b1 + e * FF;
        __syncthreads();                       // all rank reads done before staging
    }
    int n0 = ct * 128;
    const u16* ApA  = xg + (size_t)tok * DD + chunk;
    const u16* ApB0 = Bsrc + (size_t)(n0 + (2 * w) * 16 + rsub) * DD + chunk;
    const u16* ApB1 = Bsrc + (size_t)(n0 + (2 * w + 1) * 16 + rsub) * DD + chunk;

    float4v acc[2][4];
#pragma unroll
    for (int a = 0; a < 2; ++a)
#pragma unroll
        for (int b = 0; b < 4; ++b) acc[a][b] = (float4v){0.f, 0.f, 0.f, 0.f};

#define STAGE_A(K0, AX, BX)                                         \
    { gl_lds16(ApA + (K0), AX + w * 512);                           \
      gl_lds16(ApB0 + (K0), BX + (2 * w) * 512);                    \
      gl_lds16(ApB1 + (K0), BX + (2 * w + 1) * 512); }
#define COMP(AX, BX)                                                \
    { int slot = (quad ^ ((ln >> 1) & 3)) * 8;                      \
      short8 Af[2], Bf[4];                                          \
      _Pragma("unroll")                                             \
      for (int a = 0; a < 2; ++a)                                   \
          Af[a] = *(const short8*)&AX[((w & 1) * 32 + a * 16 + ln) * 32 + slot]; \
      _Pragma("unroll")                                             \
      for (int b = 0; b < 4; ++b)                                   \
          Bf[b] = *(const short8*)&BX[((w >> 1) * 64 + b * 16 + ln) * 32 + slot]; \
      _Pragma("unroll")                                             \
      for (int a = 0; a < 2; ++a)                                   \
          _Pragma("unroll")                                         \
          for (int b = 0; b < 4; ++b)                               \
              acc[a][b] = __builtin_amdgcn_mfma_f32_16x16x32_bf16(Af[a], Bf[b], acc[a][b], 0, 0, 0); }

    STAGE_A(0, As0, Bs0);
    for (int kt = 0; kt < 16; kt += 2) {
        __syncthreads();                       // drains prev stage (vmcnt) + WAR
        STAGE_A((kt + 1) * 32, As1, Bs1);      // kt+1 <= 15 always valid
        COMP(As0, Bs0);
        __syncthreads();
        if (kt + 2 < 16) STAGE_A((kt + 2) * 32, As0, Bs0);
        COMP(As1, Bs1);
    }
#pragma unroll
    for (int b = 0; b < 4; ++b) {
        int n = n0 + (w >> 1) * 64 + b * 16 + ln;
        float bv = bias[n];
#pragma unroll
        for (int a = 0; a < 2; ++a) {
#pragma unroll
            for (int i = 0; i < 4; ++i) {
                int lr = (w & 1) * 32 + a * 16 + quad * 4 + i;
                if (lr < Mloc) {
                    float v = acc[a][b][i] + bv;
                    v = v > 0.f ? v : 0.f;
                    hbuf[(size_t)(hRowBase + lr) * FF + n] = f2bf(v);
                }
            }
        }
    }
#undef STAGE_A
#undef COMP
}

// ---------------- GEMM B: out[t] += w*(h @ W2 + b2). M=64,N=128,BK=32, dbuf -----
// jobs: [0,256) shared (rt5|ct2|ks1); [256,2304): jr = (rt*8+ct*2+ks)*8 + e.
__global__ __launch_bounds__(256) void gemmB_k(
    const u16* __restrict__ hbuf, const u16* __restrict__ Wt2,
    const float* __restrict__ b2, const float* __restrict__ bs2,
    const int* __restrict__ metaE, const float* __restrict__ metaW,
    float* __restrict__ out) {
    __shared__ __align__(16) u16 As0[64 * 32];
    __shared__ __align__(16) u16 As1[64 * 32];
    __shared__ __align__(16) u16 Bs0[128 * 32];
    __shared__ __align__(16) u16 Bs1[128 * 32];
    int j = blockIdx.x, tid = threadIdx.x;
    int lane = tid & 63, w = tid >> 6, ln = lane & 15, quad = lane >> 4;
    int rsub = lane >> 2;
    int chunk = ((lane & 3) ^ ((lane >> 3) & 3)) * 8;

    int rt, ct, ks, Mloc, aRowBase; bool sh = (j < 256);
    const u16* Bsrc; const float* bias;
    int tokv[8]; float wrv[8];
    if (sh) {
        rt = j >> 3; int sub = j & 7; ct = sub >> 1; ks = sub & 1;
        Mloc = 64; aRowBase = 4096 + rt * 64;
        Bsrc = Wt2 + (size_t)8 * DD * FF; bias = bs2;
#pragma unroll
        for (int a = 0; a < 2; ++a)
#pragma unroll
            for (int i = 0; i < 4; ++i) {
                int row = aRowBase + (w & 1) * 32 + a * 16 + quad * 4 + i;
                tokv[a * 4 + i] = row - 4096; wrv[a * 4 + i] = 0.5f;
            }
    } else {
        int jr = j - 256; int e = jr & 7; int rc = jr >> 3;
        rt = rc >> 3; ct = (rc >> 1) & 3; ks = rc & 1;
        u16* er = Bs0; u16* row2ent = Bs1;
        int* scanA = (int*)As0; int* scanB = scanA + 512;
        int* offs8 = (int*)As1;
        int* pref;
        rank_inblock(metaE, er, scanA, scanB, offs8, row2ent, tid, w, lane, &pref);
        int myCnt = pref[504 + e];
        if (rt * 64 >= myCnt) return;
        rank_scatter(er, pref, offs8, row2ent, tid);
        __syncthreads();
        aRowBase = offs8[e] + rt * 64;
        Mloc = myCnt - rt * 64; if (Mloc > 64) Mloc = 64;
#pragma unroll
        for (int a = 0; a < 2; ++a)
#pragma unroll
            for (int i = 0; i < 4; ++i) {
                int row = aRowBase + (w & 1) * 32 + a * 16 + quad * 4 + i;
                if (row > 4095) row = 4095;
                int ent = row2ent[row];
                tokv[a * 4 + i] = ent >> 1;
                wrv[a * 4 + i] = metaW[ent];
            }
        Bsrc = Wt2 + (size_t)e * DD * FF; bias = b2 + e * DD;
        __syncthreads();                       // rank reads done before staging
    }
    int n0 = ct * 128;
    {
        // per-lane A row for staging needs row2ent too (routed) - recompute tok:
        // A rows: aRowBase + w*16 + rsub  -> for routed, map through bucket:
    }
    const u16* ApA = hbuf + (size_t)(aRowBase + w * 16 + rsub) * FF + ks * 1024 + chunk;
    const u16* ApB0 = Bsrc + (size_t)(n0 + (2 * w) * 16 + rsub) * FF + ks * 1024 + chunk;
    const u16* ApB1 = Bsrc + (size_t)(n0 + (2 * w + 1) * 16 + rsub) * FF + ks * 1024 + chunk;

    float4v acc[2][4];
#pragma unroll
    for (int a = 0; a < 2; ++a)
#pragma unroll
        for (int b = 0; b < 4; ++b) acc[a][b] = (float4v){0.f, 0.f, 0.f, 0.f};

#define STAGE_B(K0, AX, BX)                                         \
    { gl_lds16(ApA + (K0), AX + w * 512);                           \
      gl_lds16(ApB0 + (K0), BX + (2 * w) * 512);                    \
      gl_lds16(ApB1 + (K0), BX + (2 * w + 1) * 512); }
#define COMP(AX, BX)                                                \
    { int slot = (quad ^ ((ln >> 1) & 3)) * 8;                      \
      short8 Af[2], Bf[4];                                          \
      _Pragma("unroll")                                             \
      for (int a = 0; a < 2; ++a)                                   \
          Af[a] = *(const short8*)&AX[((w & 1) * 32 + a * 16 + ln) * 32 + slot]; \
      _Pragma("unroll")                                             \
      for (int b = 0; b < 4; ++b)                                   \
          Bf[b] = *(const short8*)&BX[((w >> 1) * 64 + b * 16 + ln) * 32 + slot]; \
      _Pragma("unroll")                                             \
      for (int a = 0; a < 2; ++a)                                   \
          _Pragma("unroll")                                         \
          for (int b = 0; b < 4; ++b)                               \
              acc[a][b] = __builtin_amdgcn_mfma_f32_16x16x32_bf16(Af[a], Bf[b], acc[a][b], 0, 0, 0); }

    STAGE_B(0, As0, Bs0);
    for (int kt = 0; kt < 32; kt += 2) {
        __syncthreads();
        STAGE_B((kt + 1) * 32, As1, Bs1);      // kt+1 <= 31 always valid
        COMP(As0, Bs0);
        __syncthreads();
        if (kt + 2 < 32) STAGE_B((kt + 2) * 32, As0, Bs0);
        COMP(As1, Bs1);
    }
    float bv[4];
#pragma unroll
    for (int b = 0; b < 4; ++b)
        bv[b] = (ks == 0) ? bias[n0 + (w >> 1) * 64 + b * 16 + ln] : 0.f;
#pragma unroll
    for (int a = 0; a < 2; ++a) {
#pragma unroll
        for (int i = 0; i < 4; ++i) {
            int lr = (w & 1) * 32 + a * 16 + quad * 4 + i;
            if (lr < Mloc) {
                float* op = out + (size_t)tokv[a * 4 + i] * DD;
                float wr = wrv[a * 4 + i];
#pragma unroll
                for (int b = 0; b < 4; ++b) {
                    int n = n0 + (w >> 1) * 64 + b * 16 + ln;
                    atomicAdd(op + n, wr * (acc[a][b][i] + bv[b]));
                }
            }
        }
    }
#undef STAGE_B
#undef COMP
}

// ---------------- launcher: 3 nodes (big path) ----------------
extern "C" void kernel_launch(void* const* d_in, const int* in_sizes, int n_in,
                              void* d_out, int out_size, void* d_ws, size_t ws_size,
                              hipStream_t stream) {
    const float* x   = (const float*)d_in[0];
    const float* Wg  = (const float*)d_in[1];
    const float* bg  = (const float*)d_in[2];
    const float* W1  = (const float*)d_in[3];
    const float* b1  = (const float*)d_in[4];
    const float* W2  = (const float*)d_in[5];
    const float* b2  = (const float*)d_in[6];
    const float* Ws1 = (const float*)d_in[7];
    const float* bs1 = (const float*)d_in[8];
    const float* Ws2 = (const float*)d_in[9];
    const float* bs2 = (const float*)d_in[10];
    float* out = (float*)d_out;

    char* ws = (char*)d_ws;
    u16*   hbuf  = (u16*)(ws + WS_HB);
    u16*   xg    = (u16*)(ws + WS_XG);
    u16*   Wt1   = (u16*)(ws + WS_WT1);
    int*   metaE = (int*)(ws + WS_ME);
    float* metaW = (float*)(ws + WS_MW);
    bool   big   = ws_size >= WS_NEED;
    u16*   Wt2   = big ? (u16*)(ws + WS_WT2) : Wt1;
    int    nconv = big ? 4608 : 2304;

    fused1_k<<<nconv + 640, 256, 0, stream>>>(x, Wg, bg, W1, Ws1, W2, Ws2,
                                              out, xg, Wt1, Wt2, metaE, metaW, nconv);
    gemmA_k<<<4608, 256, 0, stream>>>(xg, Wt1, b1, bs1, metaE, metaW, hbuf);
    if (!big) conv2_k<<<2304, 256, 0, stream>>>(W2, Ws2, Wt2);
    gemmB_k<<<2304, 256, 0, stream>>>(hbuf, Wt2, b2, bs2, metaE, metaW, out);
}

// Round 11
// 235.173 us; speedup vs baseline: 1.0248x; 1.0248x over previous
//
#include <hip/hip_runtime.h>
#include <hip/hip_bf16.h>
#include <stdint.h>

// Problem constants (S=1024, B=2 -> T=2048 tokens)
#define TT 2048
#define DD 512
#define FF 2048
#define EE 8

typedef unsigned short u16;
typedef __attribute__((ext_vector_type(8))) unsigned short ushort8v;
typedef __attribute__((ext_vector_type(8))) short short8;     // bf16x8 frag
typedef __attribute__((ext_vector_type(4))) float float4v;

__device__ __forceinline__ u16 f2bf(float f) {
    unsigned u = __float_as_uint(f);
    u += 0x7FFF + ((u >> 16) & 1);   // round-to-nearest-even
    return (u16)(u >> 16);
}

__device__ __forceinline__ void gl_lds16(const u16* g, u16* l) {
    __builtin_amdgcn_global_load_lds(
        (const __attribute__((address_space(1))) unsigned int*)g,
        (__attribute__((address_space(3))) unsigned int*)l, 16, 0, 0);
}

// ---------------- workspace layout (bytes) ----------------
#define WS_HB   0ull                                // hbuf bf16 [6144][2048]
#define WS_XG   (WS_HB + 6144ull*2048*2)            // xg bf16 [2048][512]
#define WS_WT1  (WS_XG + 2048ull*512*2)             // W1t bf16 [9][F][D]
#define WS_ME   (WS_WT1 + 9ull*2048*512*2)          // int  metaE[4096]
#define WS_MW   (WS_ME + 16384)                     // float metaW[4096]
#define WS_RT   (WS_MW + 16384)                     // int  rtok[4096]
#define WS_WROW (WS_RT + 16384)                     // float wrow[4096]
#define WS_RTG  (WS_WROW + 16384)                   // routing int[32]: offs8,cnt8,njA,njB
#define WS_JA   (WS_RTG + 128)                      // jobA int[2048]
#define WS_JB   (WS_JA + 8192)                      // jobB int[1024]
#define WS_GD   (WS_JB + 4096)                      // gateDone int (memset 0 per launch)
#define WS_WT2  (WS_GD + 64)                        // W2t bf16 [9][D][F]
#define WS_NEED (WS_WT2 + 9ull*2048*512*2)          // ~65.1 MB

// ---------------- conv unit: fp32 [R][C] 64x64 tile -> bf16 [C][R] ----------------
__device__ __forceinline__ void conv_unit(int j, const float* __restrict__ srcE,
                                          const float* __restrict__ srcS,
                                          u16* __restrict__ dst,
                                          int R, int C, int shC, u16* Ls) {
    int mid = j >> 8, t2 = j & 255;
    int tr = t2 >> shC, tc = t2 & ((1 << shC) - 1);
    int r0 = tr * 64, c0 = tc * 64;
    const float* src = (mid < 8) ? srcE + (size_t)mid * R * C : srcS;
    u16* dstm = dst + (size_t)mid * R * C;
    int t = threadIdx.x;
#pragma unroll
    for (int i = 0; i < 4; ++i) {
        int rr = (t >> 4) + i * 16;
        int cc = (t & 15) * 4;
        float4v v = *(const float4v*)(src + (size_t)(r0 + rr) * C + c0 + cc);
#pragma unroll
        for (int jx = 0; jx < 4; ++jx) Ls[(cc + jx) * 72 + rr] = f2bf(v[jx]);
    }
    __syncthreads();
#pragma unroll
    for (int jj = 0; jj < 2; ++jj) {
        int slot = t + jj * 256;
        int cc = slot >> 3, r8 = (slot & 7) * 8;
        ushort8v o = *(const ushort8v*)&Ls[cc * 72 + r8];
        *(ushort8v*)(dstm + (size_t)(c0 + cc) * R + r0 + r8) = o;
    }
}

// ---------------- gate: one wave per token (fp32 logits = np ref) ----------------
// meta written via device-scope atomicExch (coherence point; rank spin-reads later).
__device__ __forceinline__ void gate_wave(int t, int lane,
                                          const float* __restrict__ x,
                                          const float* __restrict__ Wg,
                                          const float* __restrict__ bg,
                                          int* __restrict__ metaE,
                                          float* __restrict__ metaW,
                                          u16* __restrict__ xg) {
    const float* xp = x + (size_t)t * DD + lane * 8;
    float4v x0 = *(const float4v*)xp;
    float4v x1 = *(const float4v*)(xp + 4);
    float xf[8] = {x0[0], x0[1], x0[2], x0[3], x1[0], x1[1], x1[2], x1[3]};
    float acc[EE] = {0.f, 0.f, 0.f, 0.f, 0.f, 0.f, 0.f, 0.f};
#pragma unroll
    for (int g = 0; g < 8; ++g) {
        const float* wp = Wg + (size_t)(lane * 8 + g) * EE;
        float4v w0 = *(const float4v*)wp;
        float4v w1 = *(const float4v*)(wp + 4);
        acc[0] += xf[g] * w0[0]; acc[1] += xf[g] * w0[1];
        acc[2] += xf[g] * w0[2]; acc[3] += xf[g] * w0[3];
        acc[4] += xf[g] * w1[0]; acc[5] += xf[g] * w1[1];
        acc[6] += xf[g] * w1[2]; acc[7] += xf[g] * w1[3];
    }
#pragma unroll
    for (int off = 1; off < 64; off <<= 1) {
#pragma unroll
        for (int e = 0; e < EE; ++e) acc[e] += __shfl_xor(acc[e], off, 64);
    }
    ushort8v xv;
#pragma unroll
    for (int jx = 0; jx < 4; ++jx) xv[jx] = f2bf(x0[jx]);
#pragma unroll
    for (int jx = 0; jx < 4; ++jx) xv[4 + jx] = f2bf(x1[jx]);
    *(ushort8v*)(xg + (size_t)t * DD + lane * 8) = xv;
    if (lane == 0) {
#pragma unroll
        for (int e = 0; e < EE; ++e) acc[e] += bg[e];
        int e0 = 0; float l0 = acc[0];
#pragma unroll
        for (int e = 1; e < EE; ++e) if (acc[e] > l0) { l0 = acc[e]; e0 = e; }
        int e1 = -1; float l1 = -3.4e38f;
#pragma unroll
        for (int e = 0; e < EE; ++e)
            if (e != e0 && acc[e] > l1) { l1 = acc[e]; e1 = e; }
        float ex = __expf(l1 - l0);
        float w0 = 1.f / (1.f + ex);
        atomicExch(&metaE[2 * t], e0);
        atomicExch(&metaE[2 * t + 1], e1);
        atomicExch(&metaW[2 * t], w0);
        atomicExch(&metaW[2 * t + 1], 1.f - w0);
    }
}

// ---------------- fused1: conv1 + gate + out-zero + (last block) spin-rank --------
// blocks: [0,2304) conv1; [2304,2816) gate; [2816,2944) zero; 2944 rank.
__global__ __launch_bounds__(256) void fused1_k(
    const float* __restrict__ x, const float* __restrict__ Wg,
    const float* __restrict__ bg,
    const float* __restrict__ W1, const float* __restrict__ Ws1,
    float* __restrict__ out, u16* __restrict__ xg, u16* __restrict__ Wt1,
    int* __restrict__ metaE, float* __restrict__ metaW,
    int* __restrict__ rtok, float* __restrict__ wrow,
    int* __restrict__ routing, int* __restrict__ jobA, int* __restrict__ jobB,
    int* __restrict__ gateDone) {
    __shared__ __align__(16) char smem[16384];
    int b = blockIdx.x, tid = threadIdx.x;
    if (b < 2304) {
        conv_unit(b, W1, Ws1, Wt1, DD, FF, 5, (u16*)smem);
    } else if (b < 2816) {
        int gb = b - 2304;
        gate_wave(gb * 4 + (tid >> 6), tid & 63, x, Wg, bg, metaE, metaW, xg);
        __syncthreads();
        if (tid == 0) { __threadfence(); atomicAdd(gateDone, 1); }
    } else if (b < 2944) {
        int zb = b - 2816;
        float* op = out + (size_t)zb * 8192;
#pragma unroll
        for (int it = 0; it < 8; ++it)
            *(float4v*)(op + it * 1024 + tid * 4) = (float4v){0.f, 0.f, 0.f, 0.f};
    } else {
        // ---- rank block: spin until all 512 gate blocks published ----
        if (tid == 0) {
            while (atomicAdd(gateDone, 0) < 512) __builtin_amdgcn_s_sleep(8);
            __threadfence();
        }
        __syncthreads();
        u16* er      = (u16*)smem;            // 4096 x u16 (e | rk<<4)
        int* segCnt  = (int*)(smem + 8192);   // [64][8]
        int* segBase = (int*)(smem + 10240);  // [64][8]
        int* expTot  = (int*)(smem + 12288);  // [16] + nrt/base scratch
        int wv = tid >> 6, lane = tid & 63;
        unsigned long long below = (lane == 0) ? 0ull : ((~0ull) >> (64 - lane));
        for (int s = wv * 16; s < wv * 16 + 16; ++s) {
            int entry = s * 64 + lane;
            int e = metaE[entry];
            int rk = 0;
#pragma unroll
            for (int ee = 0; ee < 8; ++ee) {
                unsigned long long m = __ballot(e == ee);
                if (e == ee) rk = __popcll(m & below);
                if (lane == ee) segCnt[s * 8 + ee] = __popcll(m);
            }
            er[entry] = (u16)(e | (rk << 4));
        }
        __syncthreads();
        if (tid < 8) {
            int s = 0;
            for (int g = 0; g < 64; ++g) { segBase[g * 8 + tid] = s; s += segCnt[g * 8 + tid]; }
            expTot[tid] = s;
        }
        __syncthreads();
        if (tid == 0) {
            int s = 0;
            for (int e = 0; e < 8; ++e) { int c = expTot[e]; expTot[8 + e] = s; s += c; }
        }
        __syncthreads();
        if (tid < 8) { routing[tid] = expTot[8 + tid]; routing[8 + tid] = expTot[tid]; }
        for (int i = 0; i < 16; ++i) {
            int entry = tid + i * 256;
            int v = er[entry];
            int e = v & 15, rk = v >> 4;
            int row = expTot[8 + e] + segBase[(entry >> 6) * 8 + e] + rk;
            rtok[row] = entry >> 1;
            wrow[row] = metaW[entry];
        }
        // ---- packed job tables ----
        __shared__ int nrt[8], baseA[8], baseB[8];
        if (tid == 0) {
            int sA = 0, sB = 0;
            for (int e = 0; e < 8; ++e) {
                int r = (expTot[e] + 63) >> 6;
                nrt[e] = r; baseA[e] = sA; baseB[e] = sB;
                sA += r * 16; sB += r * 8;
            }
            routing[16] = sA; routing[17] = sB;
        }
        __syncthreads();
        for (int e = 0; e < 8; ++e) {
            int nA = nrt[e] * 16;
            for (int i = tid; i < nA; i += 256)
                jobA[baseA[e] + i] = e | ((i >> 4) << 3) | ((i & 15) << 9);
            int nB = nrt[e] * 8;
            for (int i = tid; i < nB; i += 256)
                jobB[baseB[e] + i] = e | ((i >> 3) << 3) | ((i & 7) << 9);
        }
    }
}

// ---------------- conv2 standalone (small-ws fallback) ----------------
__global__ __launch_bounds__(256) void conv2_k(const float* __restrict__ W2,
                                               const float* __restrict__ Ws2,
                                               u16* __restrict__ Wt2) {
    __shared__ __align__(16) u16 Ls[64 * 72];
    conv_unit(blockIdx.x, W2, Ws2, Wt2, FF, DD, 3, Ls);
}

// ---------------- GEMM A (M=64,N=128,BK=64 two-plane) + overlapped conv2 ---------
// blocks: [0,2304) conv2 (big path); [2304,2816) shared (rt5|ct4); [2816,...) packed.
__global__ __launch_bounds__(256) void gemmA_k(
    const u16* __restrict__ xg, const u16* __restrict__ Wt1,
    const float* __restrict__ b1, const float* __restrict__ bs1,
    const int* __restrict__ routing, const int* __restrict__ rtok,
    const int* __restrict__ jobA, u16* __restrict__ hbuf,
    const float* __restrict__ W2, const float* __restrict__ Ws2,
    u16* __restrict__ Wt2, int doConv2) {
    __shared__ __align__(16) u16 As[2 * 64 * 32];    // 8 KB
    __shared__ __align__(16) u16 Bs[2 * 128 * 32];   // 16 KB
    int j = blockIdx.x, tid = threadIdx.x;
    if (j < 2304) {
        if (doConv2) conv_unit(j, W2, Ws2, Wt2, FF, DD, 3, As);
        return;
    }
    int rt, ct, Mloc, hRowBase, rowBase; bool routed;
    const u16* Bsrc; const float* bias;
    if (j < 2816) {
        int idx = j - 2304;
        rt = idx >> 4; ct = idx & 15; Mloc = 64; rowBase = rt * 64;
        Bsrc = Wt1 + (size_t)8 * FF * DD; bias = bs1;
        hRowBase = 4096 + rt * 64; routed = false;
    } else {
        int idx = j - 2816;
        if (idx >= routing[16]) return;
        int v = jobA[idx];
        int e = v & 7; rt = (v >> 3) & 63; ct = v >> 9;
        int M = routing[8 + e];
        rowBase = routing[e] + rt * 64;
        Mloc = M - rt * 64; if (Mloc > 64) Mloc = 64;
        Bsrc = Wt1 + (size_t)e * FF * DD; bias = b1 + e * FF;
        hRowBase = rowBase; routed = true;
    }
    int n0 = ct * 128;
    int lane = tid & 63, w = tid >> 6, ln = lane & 15, quad = lane >> 4;
    int rsub = lane >> 2;
    int chunk = ((lane & 3) ^ ((lane >> 3) & 3)) * 8;  // 0-conflict swizzle
    const u16 *Ab[2], *Bb[2][2];
    {
        int r = w * 16 + rsub;
        int tok;
        if (routed) {
            int br = rowBase + r; if (br > 4095) br = 4095;   // finite, masked below
            tok = rtok[br];
        } else tok = rowBase + r;
#pragma unroll
        for (int q = 0; q < 2; ++q) Ab[q] = xg + (size_t)tok * DD + q * 32 + chunk;
#pragma unroll
        for (int i = 0; i < 2; ++i) {
            int nl = (2 * w + i) * 16 + rsub;
#pragma unroll
            for (int q = 0; q < 2; ++q)
                Bb[i][q] = Bsrc + (size_t)(n0 + nl) * DD + q * 32 + chunk;
        }
    }
    float4v acc[2][4];
#pragma unroll
    for (int a = 0; a < 2; ++a)
#pragma unroll
        for (int b = 0; b < 4; ++b) acc[a][b] = (float4v){0.f, 0.f, 0.f, 0.f};
    for (int kt = 0; kt < 8; ++kt) {
        int k0 = kt * 64;
#pragma unroll
        for (int q = 0; q < 2; ++q) {
            gl_lds16(Ab[q] + k0, &As[q * 2048 + w * 512]);
            gl_lds16(Bb[0][q] + k0, &Bs[q * 4096 + (2 * w) * 512]);
            gl_lds16(Bb[1][q] + k0, &Bs[q * 4096 + (2 * w + 1) * 512]);
        }
        __syncthreads();
        int slot = (quad ^ ((ln >> 1) & 3)) * 8;
#pragma unroll
        for (int s = 0; s < 2; ++s) {
            short8 Af[2], Bf[4];
#pragma unroll
            for (int a = 0; a < 2; ++a)
                Af[a] = *(const short8*)&As[s * 2048 + ((w & 1) * 32 + a * 16 + ln) * 32 + slot];
#pragma unroll
            for (int b = 0; b < 4; ++b)
                Bf[b] = *(const short8*)&Bs[s * 4096 + ((w >> 1) * 64 + b * 16 + ln) * 32 + slot];
#pragma unroll
            for (int a = 0; a < 2; ++a)
#pragma unroll
                for (int b = 0; b < 4; ++b)
                    acc[a][b] = __builtin_amdgcn_mfma_f32_16x16x32_bf16(Af[a], Bf[b], acc[a][b], 0, 0, 0);
        }
        __syncthreads();
    }
#pragma unroll
    for (int b = 0; b < 4; ++b) {
        int n = n0 + (w >> 1) * 64 + b * 16 + ln;
        float bv = bias[n];
#pragma unroll
        for (int a = 0; a < 2; ++a) {
#pragma unroll
            for (int i = 0; i < 4; ++i) {
                int lr = (w & 1) * 32 + a * 16 + quad * 4 + i;
                if (lr < Mloc) {
                    float v = acc[a][b][i] + bv;
                    v = v > 0.f ? v : 0.f;
                    hbuf[(size_t)(hRowBase + lr) * FF + n] = f2bf(v);
                }
            }
        }
    }
}

// ---------------- GEMM B (M=64,N=128,BK=64, K-split x2, atomics, packed) ----------
// blocks: [0,256) shared (rt5|ct2|ks1); [256,1280) packed routed.
__global__ __launch_bounds__(256) void gemmB_k(
    const u16* __restrict__ hbuf, const u16* __restrict__ Wt2,
    const float* __restrict__ b2, const float* __restrict__ bs2,
    const int* __restrict__ routing, const int* __restrict__ rtok,
    const float* __restrict__ wrow, const int* __restrict__ jobB,
    float* __restrict__ out) {
    __shared__ __align__(16) u16 As[2 * 64 * 32];
    __shared__ __align__(16) u16 Bs[2 * 128 * 32];
    int j = blockIdx.x, tid = threadIdx.x;
    int rt, ct, ks, Mloc, aRowBase; bool sh;
    const u16* Bsrc; const float* bias;
    if (j < 256) {
        sh = true; rt = j >> 3; int sub = j & 7; ct = sub >> 1; ks = sub & 1;
        Mloc = 64; aRowBase = 4096 + rt * 64;
        Bsrc = Wt2 + (size_t)8 * DD * FF; bias = bs2;
    } else {
        sh = false;
        int idx = j - 256;
        if (idx >= routing[17]) return;
        int v = jobB[idx];
        int e = v & 7; rt = (v >> 3) & 63; int sub = v >> 9;
        ct = sub >> 1; ks = sub & 1;
        int M = routing[8 + e];
        aRowBase = routing[e] + rt * 64;
        Mloc = M - rt * 64; if (Mloc > 64) Mloc = 64;
        Bsrc = Wt2 + (size_t)e * DD * FF; bias = b2 + e * DD;
    }
    int n0 = ct * 128;
    int lane = tid & 63, w = tid >> 6, ln = lane & 15, quad = lane >> 4;
    int rsub = lane >> 2;
    int chunk = ((lane & 3) ^ ((lane >> 3) & 3)) * 8;
    const u16 *Ab[2], *Bb[2][2];
    {
        int r = w * 16 + rsub;
#pragma unroll
        for (int q = 0; q < 2; ++q)
            Ab[q] = hbuf + (size_t)(aRowBase + r) * FF + ks * 1024 + q * 32 + chunk;
#pragma unroll
        for (int i = 0; i < 2; ++i) {
            int nl = (2 * w + i) * 16 + rsub;
#pragma unroll
            for (int q = 0; q < 2; ++q)
                Bb[i][q] = Bsrc + (size_t)(n0 + nl) * FF + ks * 1024 + q * 32 + chunk;
        }
    }
    float4v acc[2][4];
#pragma unroll
    for (int a = 0; a < 2; ++a)
#pragma unroll
        for (int b = 0; b < 4; ++b) acc[a][b] = (float4v){0.f, 0.f, 0.f, 0.f};
    for (int kt = 0; kt < 16; ++kt) {
        int k0 = kt * 64;
#pragma unroll
        for (int q = 0; q < 2; ++q) {
            gl_lds16(Ab[q] + k0, &As[q * 2048 + w * 512]);
            gl_lds16(Bb[0][q] + k0, &Bs[q * 4096 + (2 * w) * 512]);
            gl_lds16(Bb[1][q] + k0, &Bs[q * 4096 + (2 * w + 1) * 512]);
        }
        __syncthreads();
        int slot = (quad ^ ((ln >> 1) & 3)) * 8;
#pragma unroll
        for (int s = 0; s < 2; ++s) {
            short8 Af[2], Bf[4];
#pragma unroll
            for (int a = 0; a < 2; ++a)
                Af[a] = *(const short8*)&As[s * 2048 + ((w & 1) * 32 + a * 16 + ln) * 32 + slot];
#pragma unroll
            for (int b = 0; b < 4; ++b)
                Bf[b] = *(const short8*)&Bs[s * 4096 + ((w >> 1) * 64 + b * 16 + ln) * 32 + slot];
#pragma unroll
            for (int a = 0; a < 2; ++a)
#pragma unroll
                for (int b = 0; b < 4; ++b)
                    acc[a][b] = __builtin_amdgcn_mfma_f32_16x16x32_bf16(Af[a], Bf[b], acc[a][b], 0, 0, 0);
        }
        __syncthreads();
    }
    float bv[4];
#pragma unroll
    for (int b = 0; b < 4; ++b)
        bv[b] = (ks == 0) ? bias[n0 + (w >> 1) * 64 + b * 16 + ln] : 0.f;
#pragma unroll
    for (int a = 0; a < 2; ++a) {
#pragma unroll
        for (int i = 0; i < 4; ++i) {
            int lr = (w & 1) * 32 + a * 16 + quad * 4 + i;
            if (lr < Mloc) {
                int row = aRowBase + lr;
                int t; float wr;
                if (sh) { t = row - 4096; wr = 0.5f; }
                else    { t = rtok[row]; wr = wrow[row]; }
                float* op = out + (size_t)t * DD;
#pragma unroll
                for (int b = 0; b < 4; ++b) {
                    int n = n0 + (w >> 1) * 64 + b * 16 + ln;
                    atomicAdd(op + n, wr * (acc[a][b][i] + bv[b]));
                }
            }
        }
    }
}

// ---------------- launcher: 3 kernel nodes + tiny memset ----------------
extern "C" void kernel_launch(void* const* d_in, const int* in_sizes, int n_in,
                              void* d_out, int out_size, void* d_ws, size_t ws_size,
                              hipStream_t stream) {
    const float* x   = (const float*)d_in[0];
    const float* Wg  = (const float*)d_in[1];
    const float* bg  = (const float*)d_in[2];
    const float* W1  = (const float*)d_in[3];
    const float* b1  = (const float*)d_in[4];
    const float* W2  = (const float*)d_in[5];
    const float* b2  = (const float*)d_in[6];
    const float* Ws1 = (const float*)d_in[7];
    const float* bs1 = (const float*)d_in[8];
    const float* Ws2 = (const float*)d_in[9];
    const float* bs2 = (const float*)d_in[10];
    float* out = (float*)d_out;

    char* ws = (char*)d_ws;
    u16*   hbuf    = (u16*)(ws + WS_HB);
    u16*   xg      = (u16*)(ws + WS_XG);
    u16*   Wt1     = (u16*)(ws + WS_WT1);
    int*   metaE   = (int*)(ws + WS_ME);
    float* metaW   = (float*)(ws + WS_MW);
    int*   rtok    = (int*)(ws + WS_RT);
    float* wrow    = (float*)(ws + WS_WROW);
    int*   routing = (int*)(ws + WS_RTG);
    int*   jobA    = (int*)(ws + WS_JA);
    int*   jobB    = (int*)(ws + WS_JB);
    int*   gateDone = (int*)(ws + WS_GD);
    bool   big     = ws_size >= WS_NEED;
    u16*   Wt2     = big ? (u16*)(ws + WS_WT2) : Wt1;

    hipMemsetAsync(gateDone, 0, 4, stream);
    fused1_k<<<2945, 256, 0, stream>>>(x, Wg, bg, W1, Ws1, out, xg, Wt1,
                                       metaE, metaW, rtok, wrow,
                                       routing, jobA, jobB, gateDone);
    gemmA_k<<<4864, 256, 0, stream>>>(xg, Wt1, b1, bs1, routing, rtok, jobA, hbuf,
                                      W2, Ws2, Wt2, big ? 1 : 0);
    if (!big) conv2_k<<<2304, 256, 0, stream>>>(W2, Ws2, Wt2);
    gemmB_k<<<1280, 256, 0, stream>>>(hbuf, Wt2, b2, bs2, routing, rtok, wrow,
                                      jobB, out);
}

// Round 12
// 218.114 us; speedup vs baseline: 1.1050x; 1.0782x over previous
//
#include <hip/hip_runtime.h>
#include <hip/hip_bf16.h>
#include <stdint.h>

// Problem constants (S=1024, B=2 -> T=2048 tokens)
#define TT 2048
#define DD 512
#define FF 2048
#define EE 8

typedef unsigned short u16;
typedef __attribute__((ext_vector_type(8))) unsigned short ushort8v;
typedef __attribute__((ext_vector_type(8))) short short8;     // bf16x8 frag
typedef __attribute__((ext_vector_type(4))) float float4v;

__device__ __forceinline__ u16 f2bf(float f) {
    unsigned u = __float_as_uint(f);
    u += 0x7FFF + ((u >> 16) & 1);   // round-to-nearest-even
    return (u16)(u >> 16);
}

__device__ __forceinline__ void gl_lds16(const u16* g, u16* l) {
    __builtin_amdgcn_global_load_lds(
        (const __attribute__((address_space(1))) unsigned int*)g,
        (__attribute__((address_space(3))) unsigned int*)l, 16, 0, 0);
}

// ---------------- workspace layout (bytes) ----------------
#define WS_HB   0ull                                // hbuf bf16 [6144][2048]
#define WS_XG   (WS_HB + 6144ull*2048*2)            // xg bf16 [2048][512]
#define WS_WT1  (WS_XG + 2048ull*512*2)             // W1t bf16 [9][F][D]
#define WS_ME   (WS_WT1 + 9ull*2048*512*2)          // int  metaE[4096]
#define WS_MW   (WS_ME + 16384)                     // float metaW[4096]
#define WS_RT   (WS_MW + 16384)                     // int  rtok[4096]
#define WS_WROW (WS_RT + 16384)                     // float wrow[4096]
#define WS_RTG  (WS_WROW + 16384)                   // routing int[16] = offs[8],cnt[8]
#define WS_WT2  (WS_RTG + 128)                      // W2t bf16 [9][D][F]
#define WS_NEED (WS_WT2 + 9ull*2048*512*2)          // ~65.1 MB

// ---------------- conv unit: fp32 [R][C] 64x64 tile -> bf16 [C][R] ----------------
__device__ __forceinline__ void conv_unit(int j, const float* __restrict__ srcE,
                                          const float* __restrict__ srcS,
                                          u16* __restrict__ dst,
                                          int R, int C, int shC, u16* Ls) {
    int mid = j >> 8, t2 = j & 255;
    int tr = t2 >> shC, tc = t2 & ((1 << shC) - 1);
    int r0 = tr * 64, c0 = tc * 64;
    const float* src = (mid < 8) ? srcE + (size_t)mid * R * C : srcS;
    u16* dstm = dst + (size_t)mid * R * C;
    int t = threadIdx.x;
#pragma unroll
    for (int i = 0; i < 4; ++i) {
        int rr = (t >> 4) + i * 16;
        int cc = (t & 15) * 4;
        float4v v = *(const float4v*)(src + (size_t)(r0 + rr) * C + c0 + cc);
#pragma unroll
        for (int jx = 0; jx < 4; ++jx) Ls[(cc + jx) * 72 + rr] = f2bf(v[jx]);
    }
    __syncthreads();
#pragma unroll
    for (int jj = 0; jj < 2; ++jj) {
        int slot = t + jj * 256;
        int cc = slot >> 3, r8 = (slot & 7) * 8;
        ushort8v o = *(const ushort8v*)&Ls[cc * 72 + r8];
        *(ushort8v*)(dstm + (size_t)(c0 + cc) * R + r0 + r8) = o;
    }
}

// ---------------- gate: one wave per token (fp32 logits = np ref) ----------------
__device__ __forceinline__ void gate_wave(int t, int lane,
                                          const float* __restrict__ x,
                                          const float* __restrict__ Wg,
                                          const float* __restrict__ bg,
                                          int* __restrict__ metaE,
                                          float* __restrict__ metaW,
                                          u16* __restrict__ xg) {
    const float* xp = x + (size_t)t * DD + lane * 8;
    float4v x0 = *(const float4v*)xp;
    float4v x1 = *(const float4v*)(xp + 4);
    float xf[8] = {x0[0], x0[1], x0[2], x0[3], x1[0], x1[1], x1[2], x1[3]};
    float acc[EE] = {0.f, 0.f, 0.f, 0.f, 0.f, 0.f, 0.f, 0.f};
#pragma unroll
    for (int g = 0; g < 8; ++g) {
        const float* wp = Wg + (size_t)(lane * 8 + g) * EE;
        float4v w0 = *(const float4v*)wp;
        float4v w1 = *(const float4v*)(wp + 4);
        acc[0] += xf[g] * w0[0]; acc[1] += xf[g] * w0[1];
        acc[2] += xf[g] * w0[2]; acc[3] += xf[g] * w0[3];
        acc[4] += xf[g] * w1[0]; acc[5] += xf[g] * w1[1];
        acc[6] += xf[g] * w1[2]; acc[7] += xf[g] * w1[3];
    }
#pragma unroll
    for (int off = 1; off < 64; off <<= 1) {
#pragma unroll
        for (int e = 0; e < EE; ++e) acc[e] += __shfl_xor(acc[e], off, 64);
    }
    ushort8v xv;
#pragma unroll
    for (int jx = 0; jx < 4; ++jx) xv[jx] = f2bf(x0[jx]);
#pragma unroll
    for (int jx = 0; jx < 4; ++jx) xv[4 + jx] = f2bf(x1[jx]);
    *(ushort8v*)(xg + (size_t)t * DD + lane * 8) = xv;
    if (lane == 0) {
#pragma unroll
        for (int e = 0; e < EE; ++e) acc[e] += bg[e];
        int e0 = 0; float l0 = acc[0];
#pragma unroll
        for (int e = 1; e < EE; ++e) if (acc[e] > l0) { l0 = acc[e]; e0 = e; }
        int e1 = -1; float l1 = -3.4e38f;
#pragma unroll
        for (int e = 0; e < EE; ++e)
            if (e != e0 && acc[e] > l1) { l1 = acc[e]; e1 = e; }
        float ex = __expf(l1 - l0);
        float w0 = 1.f / (1.f + ex);
        metaE[2 * t] = e0; metaE[2 * t + 1] = e1;
        metaW[2 * t] = w0; metaW[2 * t + 1] = 1.f - w0;
    }
}

// ---------------- fused phase-1: conv1 + conv2 + gate + out-zero ----------------
__global__ __launch_bounds__(256) void fused1_k(
    const float* __restrict__ x, const float* __restrict__ Wg,
    const float* __restrict__ bg,
    const float* __restrict__ W1, const float* __restrict__ Ws1,
    const float* __restrict__ W2, const float* __restrict__ Ws2,
    float* __restrict__ out, u16* __restrict__ xg,
    u16* __restrict__ Wt1, u16* __restrict__ Wt2,
    int* __restrict__ metaE, float* __restrict__ metaW, int nconv) {
    __shared__ __align__(16) u16 Ls[64 * 72];
    int b = blockIdx.x, tid = threadIdx.x;
    if (b < nconv) {
        if (b < 2304) conv_unit(b, W1, Ws1, Wt1, DD, FF, 5, Ls);
        else          conv_unit(b - 2304, W2, Ws2, Wt2, FF, DD, 3, Ls);
    } else if (b < nconv + 512) {
        int gb = b - nconv;
        gate_wave(gb * 4 + (tid >> 6), tid & 63, x, Wg, bg, metaE, metaW, xg);
    } else {
        int zb = b - nconv - 512;
        float* op = out + (size_t)zb * 8192;
#pragma unroll
        for (int it = 0; it < 8; ++it)
            *(float4v*)(op + it * 1024 + tid * 4) = (float4v){0.f, 0.f, 0.f, 0.f};
    }
}

__global__ __launch_bounds__(256) void conv2_k(const float* __restrict__ W2,
                                               const float* __restrict__ Ws2,
                                               u16* __restrict__ Wt2) {
    __shared__ __align__(16) u16 Ls[64 * 72];
    conv_unit(blockIdx.x, W2, Ws2, Wt2, FF, DD, 3, Ls);
}

// ---------------- rank: 1 block x 256, ballot-based, 0 atomics ----------------
__global__ __launch_bounds__(256) void rank_k(const int* __restrict__ metaE,
                                              const float* __restrict__ metaW,
                                              int* __restrict__ routing,
                                              int* __restrict__ rtok,
                                              float* __restrict__ wrow) {
    __shared__ __align__(16) char smem[16384];
    u16* er      = (u16*)smem;
    int* segCnt  = (int*)(smem + 8192);
    int* segBase = (int*)(smem + 10240);
    int* expTot  = (int*)(smem + 12288);
    int tid = threadIdx.x, wv = tid >> 6, lane = tid & 63;
    unsigned long long below = (lane == 0) ? 0ull : ((~0ull) >> (64 - lane));
    for (int s = wv * 16; s < wv * 16 + 16; ++s) {
        int entry = s * 64 + lane;
        int e = metaE[entry];
        int rk = 0;
#pragma unroll
        for (int ee = 0; ee < 8; ++ee) {
            unsigned long long m = __ballot(e == ee);
            if (e == ee) rk = __popcll(m & below);
            if (lane == ee) segCnt[s * 8 + ee] = __popcll(m);
        }
        er[entry] = (u16)(e | (rk << 4));
    }
    __syncthreads();
    if (tid < 8) {
        int s = 0;
        for (int g = 0; g < 64; ++g) { segBase[g * 8 + tid] = s; s += segCnt[g * 8 + tid]; }
        expTot[tid] = s;
    }
    __syncthreads();
    if (tid == 0) {
        int s = 0;
        for (int e = 0; e < 8; ++e) { int c = expTot[e]; expTot[8 + e] = s; s += c; }
    }
    __syncthreads();
    if (tid < 8) { routing[tid] = expTot[8 + tid]; routing[8 + tid] = expTot[tid]; }
    for (int i = 0; i < 16; ++i) {
        int entry = tid + i * 256;
        int v = er[entry];
        int e = v & 15, rk = v >> 4;
        int row = expTot[8 + e] + segBase[(entry >> 6) * 8 + e] + rk;
        rtok[row] = entry >> 1;
        wrow[row] = metaW[entry];
    }
}

// ---------------- GEMM A: M=64,N=128,BK=128, 256B-contiguous staging -------------
// jobs: [0,512) shared (rt5|ct4); [512,8704) routed: jr = (rt*16+ct)*8 + e (e=XCD).
__global__ __launch_bounds__(256) void gemmA_k(
    const u16* __restrict__ xg, const u16* __restrict__ Wt1,
    const float* __restrict__ b1, const float* __restrict__ bs1,
    const int* __restrict__ routing, const int* __restrict__ rtok,
    u16* __restrict__ hbuf) {
    __shared__ __align__(16) u16 As[64 * 128];     // 16 KB
    __shared__ __align__(16) u16 Bs[128 * 128];    // 32 KB
    const int* offs = routing; const int* cnt = routing + 8;
    int j = blockIdx.x, tid = threadIdx.x;
    int rt, ct, Mloc, hRowBase, rowBase; bool routed;
    const u16* Bsrc; const float* bias;
    if (j < 512) {
        rt = j >> 4; ct = j & 15; Mloc = 64; rowBase = rt * 64;
        Bsrc = Wt1 + (size_t)8 * FF * DD; bias = bs1;
        hRowBase = 4096 + rt * 64; routed = false;
    } else {
        int jr = j - 512; int e = jr & 7; int rc = jr >> 3;
        rt = rc >> 4; ct = rc & 15;
        int M = cnt[e]; if (rt * 64 >= M) return;
        Mloc = M - rt * 64; if (Mloc > 64) Mloc = 64;
        rowBase = offs[e] + rt * 64;
        Bsrc = Wt1 + (size_t)e * FF * DD; bias = b1 + e * FF;
        hRowBase = rowBase; routed = true;
    }
    int n0 = ct * 128;
    int lane = tid & 63, w = tid >> 6, ln = lane & 15, quad = lane >> 4;
    int l4 = lane >> 4;         // row-sub 0..3 for staging
    int cpre = lane & 15;       // pre-swizzle chunk id
    // per-lane source pointers (swizzled chunk c = cpre ^ (row & 15))
    const u16* Ap[4];
#pragma unroll
    for (int i = 0; i < 4; ++i) {
        int g = i * 4 + w;                  // 0..15
        int r = g * 4 + l4;                 // 0..63
        int c = cpre ^ (r & 15);
        int tok;
        if (routed) {
            int br = rowBase + r; if (br > 4095) br = 4095;  // finite, masked below
            tok = rtok[br];
        } else tok = rowBase + r;
        Ap[i] = xg + (size_t)tok * DD + c * 8;
    }
    const u16* Bp[8];
#pragma unroll
    for (int i = 0; i < 8; ++i) {
        int g = i * 4 + w;                  // 0..31
        int r = g * 4 + l4;                 // 0..127
        int c = cpre ^ (r & 15);
        Bp[i] = Bsrc + (size_t)(n0 + r) * DD + c * 8;
    }
    float4v acc[2][4];
#pragma unroll
    for (int a = 0; a < 2; ++a)
#pragma unroll
        for (int b = 0; b < 4; ++b) acc[a][b] = (float4v){0.f, 0.f, 0.f, 0.f};
    for (int kt = 0; kt < 4; ++kt) {
        int k0 = kt * 128;
#pragma unroll
        for (int i = 0; i < 4; ++i)
            gl_lds16(Ap[i] + k0, &As[(i * 4 + w) * 512]);
#pragma unroll
        for (int i = 0; i < 8; ++i)
            gl_lds16(Bp[i] + k0, &Bs[(i * 4 + w) * 512]);
        __syncthreads();
#pragma unroll
        for (int s = 0; s < 4; ++s) {
            int slot = ((s * 4 + quad) ^ ln) * 8;
            short8 Af[2], Bf[4];
#pragma unroll
            for (int a = 0; a < 2; ++a)
                Af[a] = *(const short8*)&As[((w & 1) * 32 + a * 16 + ln) * 128 + slot];
#pragma unroll
            for (int b = 0; b < 4; ++b)
                Bf[b] = *(const short8*)&Bs[((w >> 1) * 64 + b * 16 + ln) * 128 + slot];
#pragma unroll
            for (int a = 0; a < 2; ++a)
#pragma unroll
                for (int b = 0; b < 4; ++b)
                    acc[a][b] = __builtin_amdgcn_mfma_f32_16x16x32_bf16(Af[a], Bf[b], acc[a][b], 0, 0, 0);
        }
        __syncthreads();
    }
#pragma unroll
    for (int b = 0; b < 4; ++b) {
        int n = n0 + (w >> 1) * 64 + b * 16 + ln;
        float bv = bias[n];
#pragma unroll
        for (int a = 0; a < 2; ++a) {
#pragma unroll
            for (int i = 0; i < 4; ++i) {
                int lr = (w & 1) * 32 + a * 16 + quad * 4 + i;
                if (lr < Mloc) {
                    float v = acc[a][b][i] + bv;
                    v = v > 0.f ? v : 0.f;
                    hbuf[(size_t)(hRowBase + lr) * FF + n] = f2bf(v);
                }
            }
        }
    }
}

// ---------------- GEMM B: M=64,N=128,BK=128, K-split x2, atomics -----------------
// jobs: [0,256) shared (rt5|ct2|ks1); [256,4352): jr = (rt*8+ct*2+ks)*8 + e.
__global__ __launch_bounds__(256) void gemmB_k(
    const u16* __restrict__ hbuf, const u16* __restrict__ Wt2,
    const float* __restrict__ b2, const float* __restrict__ bs2,
    const int* __restrict__ routing, const int* __restrict__ rtok,
    const float* __restrict__ wrow, float* __restrict__ out) {
    __shared__ __align__(16) u16 As[64 * 128];     // 16 KB
    __shared__ __align__(16) u16 Bs[128 * 128];    // 32 KB
    const int* offs = routing; const int* cnt = routing + 8;
    int j = blockIdx.x, tid = threadIdx.x;
    int rt, ct, ks, Mloc, aRowBase; bool sh;
    const u16* Bsrc; const float* bias;
    if (j < 256) {
        sh = true; rt = j >> 3; int sub = j & 7; ct = sub >> 1; ks = sub & 1;
        Mloc = 64; aRowBase = 4096 + rt * 64;
        Bsrc = Wt2 + (size_t)8 * DD * FF; bias = bs2;
    } else {
        sh = false; int jr = j - 256; int e = jr & 7; int rc = jr >> 3;
        rt = rc >> 3; ct = (rc >> 1) & 3; ks = rc & 1;
        int M = cnt[e]; if (rt * 64 >= M) return;
        Mloc = M - rt * 64; if (Mloc > 64) Mloc = 64;
        aRowBase = offs[e] + rt * 64;
        Bsrc = Wt2 + (size_t)e * DD * FF; bias = b2 + e * DD;
    }
    int n0 = ct * 128;
    int lane = tid & 63, w = tid >> 6, ln = lane & 15, quad = lane >> 4;
    int l4 = lane >> 4;
    int cpre = lane & 15;
    const u16* Ap[4];
#pragma unroll
    for (int i = 0; i < 4; ++i) {
        int g = i * 4 + w;
        int r = g * 4 + l4;
        int c = cpre ^ (r & 15);
        Ap[i] = hbuf + (size_t)(aRowBase + r) * FF + ks * 1024 + c * 8;
    }
    const u16* Bp[8];
#pragma unroll
    for (int i = 0; i < 8; ++i) {
        int g = i * 4 + w;
        int r = g * 4 + l4;
        int c = cpre ^ (r & 15);
        Bp[i] = Bsrc + (size_t)(n0 + r) * FF + ks * 1024 + c * 8;
    }
    float4v acc[2][4];
#pragma unroll
    for (int a = 0; a < 2; ++a)
#pragma unroll
        for (int b = 0; b < 4; ++b) acc[a][b] = (float4v){0.f, 0.f, 0.f, 0.f};
    for (int kt = 0; kt < 8; ++kt) {
        int k0 = kt * 128;
#pragma unroll
        for (int i = 0; i < 4; ++i)
            gl_lds16(Ap[i] + k0, &As[(i * 4 + w) * 512]);
#pragma unroll
        for (int i = 0; i < 8; ++i)
            gl_lds16(Bp[i] + k0, &Bs[(i * 4 + w) * 512]);
        __syncthreads();
#pragma unroll
        for (int s = 0; s < 4; ++s) {
            int slot = ((s * 4 + quad) ^ ln) * 8;
            short8 Af[2], Bf[4];
#pragma unroll
            for (int a = 0; a < 2; ++a)
                Af[a] = *(const short8*)&As[((w & 1) * 32 + a * 16 + ln) * 128 + slot];
#pragma unroll
            for (int b = 0; b < 4; ++b)
                Bf[b] = *(const short8*)&Bs[((w >> 1) * 64 + b * 16 + ln) * 128 + slot];
#pragma unroll
            for (int a = 0; a < 2; ++a)
#pragma unroll
                for (int b = 0; b < 4; ++b)
                    acc[a][b] = __builtin_amdgcn_mfma_f32_16x16x32_bf16(Af[a], Bf[b], acc[a][b], 0, 0, 0);
        }
        __syncthreads();
    }
    float bv[4];
#pragma unroll
    for (int b = 0; b < 4; ++b)
        bv[b] = (ks == 0) ? bias[n0 + (w >> 1) * 64 + b * 16 + ln] : 0.f;
#pragma unroll
    for (int a = 0; a < 2; ++a) {
#pragma unroll
        for (int i = 0; i < 4; ++i) {
            int lr = (w & 1) * 32 + a * 16 + quad * 4 + i;
            if (lr < Mloc) {
                int row = aRowBase + lr;
                int t; float wr;
                if (sh) { t = row - 4096; wr = 0.5f; }
                else    { t = rtok[row]; wr = wrow[row]; }
                float* op = out + (size_t)t * DD;
#pragma unroll
                for (int b = 0; b < 4; ++b) {
                    int n = n0 + (w >> 1) * 64 + b * 16 + ln;
                    atomicAdd(op + n, wr * (acc[a][b][i] + bv[b]));
                }
            }
        }
    }
}

// ---------------- launcher: R9 structure (4 regular nodes) ----------------
extern "C" void kernel_launch(void* const* d_in, const int* in_sizes, int n_in,
                              void* d_out, int out_size, void* d_ws, size_t ws_size,
                              hipStream_t stream) {
    const float* x   = (const float*)d_in[0];
    const float* Wg  = (const float*)d_in[1];
    const float* bg  = (const float*)d_in[2];
    const float* W1  = (const float*)d_in[3];
    const float* b1  = (const float*)d_in[4];
    const float* W2  = (const float*)d_in[5];
    const float* b2  = (const float*)d_in[6];
    const float* Ws1 = (const float*)d_in[7];
    const float* bs1 = (const float*)d_in[8];
    const float* Ws2 = (const float*)d_in[9];
    const float* bs2 = (const float*)d_in[10];
    float* out = (float*)d_out;

    char* ws = (char*)d_ws;
    u16*   hbuf    = (u16*)(ws + WS_HB);
    u16*   xg      = (u16*)(ws + WS_XG);
    u16*   Wt1     = (u16*)(ws + WS_WT1);
    int*   metaE   = (int*)(ws + WS_ME);
    float* metaW   = (float*)(ws + WS_MW);
    int*   rtok    = (int*)(ws + WS_RT);
    float* wrow    = (float*)(ws + WS_WROW);
    int*   routing = (int*)(ws + WS_RTG);
    bool   big     = ws_size >= WS_NEED;
    u16*   Wt2     = big ? (u16*)(ws + WS_WT2) : Wt1;
    int    nconv   = big ? 4608 : 2304;

    fused1_k<<<nconv + 640, 256, 0, stream>>>(x, Wg, bg, W1, Ws1, W2, Ws2,
                                              out, xg, Wt1, Wt2, metaE, metaW, nconv);
    rank_k<<<1, 256, 0, stream>>>(metaE, metaW, routing, rtok, wrow);
    gemmA_k<<<8704, 256, 0, stream>>>(xg, Wt1, b1, bs1, routing, rtok, hbuf);
    if (!big) conv2_k<<<2304, 256, 0, stream>>>(W2, Ws2, Wt2);
    gemmB_k<<<4352, 256, 0, stream>>>(hbuf, Wt2, b2, bs2, routing, rtok, wrow, out);
}